// Round 1
// baseline (109.984 us; speedup 1.0000x reference)
//
#include <hip/hip_runtime.h>
#include <math.h>

#define NB 32
#define NS 256
#define NT 64
#define NGT 16   // g-tiles of 256 (G = 4096)

// ws layout (floats):
//      0 : sortW   [NB*NS]   alpha*exp(beta*t) (0 if t<=0), sorted by t asc
//   8192 : sortX   [NB*NS]
//  16384 : sortY   [NB*NS]
//  24576 : cnt     [NB*NT]   (int) #events with t <= tc_k
//  26624 : sumlog  [NB]
//  26656 : partials[NB*NGT]
#define WS_SORTW   0
#define WS_SORTX   8192
#define WS_SORTY   16384
#define WS_CNT     24576
#define WS_SUMLOG  26624
#define WS_PART    26656

__device__ __forceinline__ float softplus_f(float x) {
    // stable: max(x,0) + log1p(exp(-|x|))  (matches jax.nn.softplus)
    return fmaxf(x, 0.0f) + log1pf(expf(-fabsf(x)));
}

__global__ void prep_kernel(const float* __restrict__ X,
                            const float* __restrict__ mu_p,
                            const float* __restrict__ alpha_p,
                            const float* __restrict__ beta_p,
                            const float* __restrict__ gamma_p,
                            float* __restrict__ out_lams,
                            float* __restrict__ ws) {
    __shared__ float ts[NS], xs[NS], ys[NS];
    __shared__ float red[4];
    const int b = blockIdx.x;
    const int i = threadIdx.x;
    const float mu = *mu_p, alpha = *alpha_p, beta = *beta_p, gamma = *gamma_p;

    const float* Xb = X + (size_t)b * NS * 3;
    const float t  = Xb[i * 3 + 0];
    const float sx = Xb[i * 3 + 1];
    const float sy = Xb[i * 3 + 2];
    ts[i] = t; xs[i] = sx; ys[i] = sy;
    __syncthreads();

    // ---- lams[b,i] = softplus(alpha * sum_{j<i, t_j>0} exp(-beta*(t_i-t_j) - gamma*d2) + mu) + 1e-5
    float acc = 0.0f;
    for (int j = 0; j < i; ++j) {
        const float tj = ts[j];
        if (tj > 0.0f) {
            const float dx = sx - xs[j];
            const float dy = sy - ys[j];
            acc += expf(-beta * (t - tj) - gamma * (dx * dx + dy * dy));
        }
    }
    const float lam = softplus_f(alpha * acc + mu) + 1e-5f;
    out_lams[b * NS + i] = lam;

    // ---- sum over valid events of log(lam)
    float logl = (t > 0.0f) ? logf(lam) : 0.0f;
    #pragma unroll
    for (int off = 32; off > 0; off >>= 1) logl += __shfl_down(logl, off, 64);
    const int wave = i >> 6, lane = i & 63;
    if (lane == 0) red[wave] = logl;
    __syncthreads();
    if (i == 0) ws[WS_SUMLOG + b] = red[0] + red[1] + red[2] + red[3];

    // ---- rank-sort events by t (ties by index) -> permutation scatter
    int rank = 0;
    for (int j = 0; j < NS; ++j) {
        const float tj = ts[j];
        rank += (tj < t) || (tj == t && j < i);
    }
    const float w = (t > 0.0f) ? alpha * expf(beta * t) : 0.0f;
    ws[WS_SORTW + b * NS + rank] = w;
    ws[WS_SORTX + b * NS + rank] = sx;
    ws[WS_SORTY + b * NS + rank] = sy;

    // ---- cnt[k] = #events with t <= tc_k   (invalid t<=0 events have w=0: harmless)
    if (i < NT) {
        const float tc = (float)i * (1.0f / 63.0f);
        int c = 0;
        for (int j = 0; j < NS; ++j) c += (ts[j] <= tc) ? 1 : 0;
        ((int*)ws)[WS_CNT + b * NT + i] = c;
    }
}

__global__ void grid_kernel(const float* __restrict__ mu_p,
                            const float* __restrict__ beta_p,
                            const float* __restrict__ gamma_p,
                            const float* __restrict__ ws,
                            float* __restrict__ partials) {
    __shared__ float wS[NS], xS[NS], yS[NS];
    __shared__ int cS[NT];
    __shared__ float red[4];
    const int blk = blockIdx.x;
    const int b = blk >> 4;      // / NGT
    const int gt = blk & (NGT - 1);
    const int tid = threadIdx.x;
    const float mu = *mu_p, beta = *beta_p, gamma = *gamma_p;

    wS[tid] = ws[WS_SORTW + b * NS + tid];
    xS[tid] = ws[WS_SORTX + b * NS + tid];
    yS[tid] = ws[WS_SORTY + b * NS + tid];
    if (tid < NT) cS[tid] = ((const int*)ws)[WS_CNT + b * NT + tid];
    __syncthreads();

    const int g = gt * 256 + tid;          // g in [0,4096)
    const float gx = (float)(g >> 6) * (1.0f / 63.0f);   // ss[i1], meshgrid 'ij'
    const float gy = (float)(g & 63) * (1.0f / 63.0f);   // ss[i2]

    float run = 0.0f, total = 0.0f;
    int p = 0;
    for (int k = 0; k < NT; ++k) {
        const int ck = cS[k];              // wave-uniform: all lanes share b
        for (; p < ck; ++p) {
            const float dx = gx - xS[p];
            const float dy = gy - yS[p];
            run += wS[p] * expf(-gamma * (dx * dx + dy * dy));
        }
        const float tc = (float)k * (1.0f / 63.0f);
        total += softplus_f(expf(-beta * tc) * run + mu);
    }

    #pragma unroll
    for (int off = 32; off > 0; off >>= 1) total += __shfl_down(total, off, 64);
    const int wave = tid >> 6, lane = tid & 63;
    if (lane == 0) red[wave] = total;
    __syncthreads();
    if (tid == 0) partials[blk] = red[0] + red[1] + red[2] + red[3];
}

__global__ void final_kernel(const float* __restrict__ ws,
                             float* __restrict__ out) {
    const int b = threadIdx.x;
    if (b < NB) {
        float s = 0.0f;
        #pragma unroll
        for (int gt = 0; gt < NGT; ++gt) s += ws[WS_PART + b * NGT + gt];
        const float unit_vol = 1.0f / 262144.0f;  // 1*1*1 / 64^3
        out[NB * NS + b] = ws[WS_SUMLOG + b] - s * unit_vol;
    }
}

extern "C" void kernel_launch(void* const* d_in, const int* in_sizes, int n_in,
                              void* d_out, int out_size, void* d_ws, size_t ws_size,
                              hipStream_t stream) {
    const float* X       = (const float*)d_in[0];
    const float* mu_p    = (const float*)d_in[1];
    const float* alpha_p = (const float*)d_in[2];
    const float* beta_p  = (const float*)d_in[3];
    const float* gamma_p = (const float*)d_in[4];
    float* out = (float*)d_out;
    float* ws  = (float*)d_ws;

    prep_kernel<<<NB, NS, 0, stream>>>(X, mu_p, alpha_p, beta_p, gamma_p, out, ws);
    grid_kernel<<<NB * NGT, 256, 0, stream>>>(mu_p, beta_p, gamma_p, ws, ws + WS_PART);
    final_kernel<<<1, 64, 0, stream>>>(ws, out);
}

// Round 2
// 41.937 us; speedup vs baseline: 2.6226x; 2.6226x over previous
//
#include <hip/hip_runtime.h>
#include <math.h>

#define NB  32
#define NS  256
#define NT  64
#define NGT 16   // g-tiles of 256 (G = 4096)
#define NTI 8    // lam tiles per batch (32 i's each)

// ws layout (float index):
//      0 : ev     float4[NB*NS]  (w, x, y, t), sorted by t asc   -> 32768 floats
//  32768 : cnt    int[NB*NT]     #events with t <= tc_k          ->  2048
//  34816 : logpart float[NB*NTI]                                 ->   256
//  35072 : gridpart float[NB*NGT]                                ->   512
#define WS_EV     0
#define WS_CNT    32768
#define WS_LOGP   34816
#define WS_GRIDP  35072

__device__ __forceinline__ float softplus_fast(float x) {
    // max(x,0) + log(1+exp(-|x|)) with native exp/log; abs err ~1e-7
    return fmaxf(x, 0.0f) + __logf(1.0f + __expf(-fabsf(x)));
}

// blocks [0,NB): sort+cnt for batch b.  blocks [NB, NB+NB*NTI): lams tile.
__global__ void prep_kernel(const float* __restrict__ X,
                            const float* __restrict__ mu_p,
                            const float* __restrict__ alpha_p,
                            const float* __restrict__ beta_p,
                            const float* __restrict__ gamma_p,
                            float* __restrict__ out_lams,
                            float* __restrict__ ws) {
    __shared__ float ts[NS], xs[NS], ys[NS];
    __shared__ float red[32];
    const int blk = blockIdx.x;
    const int tid = threadIdx.x;

    if (blk < NB) {
        // ---------- sort by t (rank-sort) + inclusion counts ----------
        const int b = blk;
        const float alpha = *alpha_p, beta = *beta_p;
        const float* Xb = X + (size_t)b * NS * 3;
        const float t  = Xb[tid * 3 + 0];
        const float sx = Xb[tid * 3 + 1];
        const float sy = Xb[tid * 3 + 2];
        ts[tid] = t;
        __syncthreads();
        int rank = 0;
        for (int j = 0; j < NS; ++j) {
            const float tj = ts[j];
            rank += (tj < t) || (tj == t && j < tid);
        }
        const float w = (t > 0.0f) ? alpha * __expf(beta * t) : 0.0f;
        ((float4*)(ws + WS_EV))[b * NS + rank] = make_float4(w, sx, sy, t);
        if (tid < NT) {
            const float tc = (float)tid * (1.0f / 63.0f);
            int c = 0;
            for (int j = 0; j < NS; ++j) c += (ts[j] <= tc) ? 1 : 0;
            ((int*)ws)[WS_CNT + b * NT + tid] = c;
        }
    } else {
        // ---------- lams: 8 threads per output i, 32-long j slices ----------
        const int lb = blk - NB;
        const int b = lb >> 3, tile = lb & (NTI - 1);
        const float mu = *mu_p, alpha = *alpha_p, beta = *beta_p, gamma = *gamma_p;
        const float* Xb = X + (size_t)b * NS * 3;
        ts[tid] = Xb[tid * 3 + 0];
        xs[tid] = Xb[tid * 3 + 1];
        ys[tid] = Xb[tid * 3 + 2];
        __syncthreads();

        const int il = tid >> 3;       // 0..31: local i
        const int jp = tid & 7;        // j-slice
        const int i  = tile * 32 + il;
        const float ti = ts[i], xi = xs[i], yi = ys[i];
        const float nbti = -beta * ti;

        float acc = 0.0f;
        const int j0 = jp * 32;
        const int j1 = (j0 + 32 < i) ? j0 + 32 : i;
        for (int j = j0; j < j1; ++j) {
            const float tj = ts[j];
            if (tj > 0.0f) {
                const float dx = xi - xs[j];
                const float dy = yi - ys[j];
                const float d2 = fmaf(dx, dx, dy * dy);
                acc += __expf(fmaf(beta, tj, nbti) - gamma * d2);
            }
        }
        acc += __shfl_down(acc, 4, 8);
        acc += __shfl_down(acc, 2, 8);
        acc += __shfl_down(acc, 1, 8);
        if (jp == 0) {
            const float lam = softplus_fast(fmaf(alpha, acc, mu)) + 1e-5f;
            out_lams[b * NS + i] = lam;
            red[il] = (ti > 0.0f) ? __logf(lam) : 0.0f;
        }
        __syncthreads();
        if (tid == 0) {
            float s = 0.0f;
            #pragma unroll
            for (int k = 0; k < 32; ++k) s += red[k];
            ws[WS_LOGP + b * NTI + tile] = s;
        }
    }
}

__global__ void grid_kernel(const float* __restrict__ mu_p,
                            const float* __restrict__ beta_p,
                            const float* __restrict__ gamma_p,
                            const float* __restrict__ ws,
                            float* __restrict__ partials) {
    __shared__ float4 evS[NS];
    __shared__ float decay[NT];
    __shared__ int   cS[NT];
    __shared__ float red[4];
    const int blk = blockIdx.x;
    const int b  = blk >> 4;            // / NGT
    const int gt = blk & (NGT - 1);
    const int tid = threadIdx.x;
    const float mu = *mu_p, beta = *beta_p, gamma = *gamma_p;

    evS[tid] = ((const float4*)(ws + WS_EV))[b * NS + tid];
    if (tid < NT) {
        cS[tid] = ((const int*)ws)[WS_CNT + b * NT + tid];
        decay[tid] = __expf(-beta * ((float)tid * (1.0f / 63.0f)));
    }
    __syncthreads();

    const int g = gt * 256 + tid;                        // g in [0,4096)
    const float gx = (float)(g >> 6) * (1.0f / 63.0f);   // meshgrid 'ij'
    const float gy = (float)(g & 63) * (1.0f / 63.0f);

    float run = 0.0f, total = 0.0f;
    int p = 0;
    for (int k = 0; k < NT; ++k) {
        const int ck = cS[k];            // wave-uniform (all lanes share b)
        for (; p < ck; ++p) {
            const float4 e = evS[p];     // one ds_read_b128 broadcast
            const float dx = gx - e.y;
            const float dy = gy - e.z;
            const float d2 = fmaf(dx, dx, dy * dy);
            run = fmaf(e.x, __expf(-gamma * d2), run);
        }
        const float z = fmaf(decay[k], run, mu);
        total += fmaxf(z, 0.0f) + __logf(1.0f + __expf(-fabsf(z)));
    }

    #pragma unroll
    for (int off = 32; off > 0; off >>= 1) total += __shfl_down(total, off, 64);
    const int wave = tid >> 6, lane = tid & 63;
    if (lane == 0) red[wave] = total;
    __syncthreads();
    if (tid == 0) partials[blk] = red[0] + red[1] + red[2] + red[3];
}

__global__ void final_kernel(const float* __restrict__ ws,
                             float* __restrict__ out) {
    const int b = threadIdx.x;
    if (b < NB) {
        float s = 0.0f;
        #pragma unroll
        for (int gt = 0; gt < NGT; ++gt) s += ws[WS_GRIDP + b * NGT + gt];
        float lg = 0.0f;
        #pragma unroll
        for (int t = 0; t < NTI; ++t) lg += ws[WS_LOGP + b * NTI + t];
        const float unit_vol = 1.0f / 262144.0f;  // 1 / 64^3
        out[NB * NS + b] = lg - s * unit_vol;
    }
}

extern "C" void kernel_launch(void* const* d_in, const int* in_sizes, int n_in,
                              void* d_out, int out_size, void* d_ws, size_t ws_size,
                              hipStream_t stream) {
    const float* X       = (const float*)d_in[0];
    const float* mu_p    = (const float*)d_in[1];
    const float* alpha_p = (const float*)d_in[2];
    const float* beta_p  = (const float*)d_in[3];
    const float* gamma_p = (const float*)d_in[4];
    float* out = (float*)d_out;
    float* ws  = (float*)d_ws;

    prep_kernel<<<NB + NB * NTI, NS, 0, stream>>>(X, mu_p, alpha_p, beta_p, gamma_p, out, ws);
    grid_kernel<<<NB * NGT, 256, 0, stream>>>(mu_p, beta_p, gamma_p, ws, ws + WS_GRIDP);
    final_kernel<<<1, NB, 0, stream>>>(ws, out);
}